// Round 15
// baseline (8182.797 us; speedup 1.0000x reference)
//
#include <hip/hip_runtime.h>
#include <math.h>

#define TPB 1024
#define NBLK 256
#define NBATCH 32
#define NGRP 4
#define GBAT 8          // batches per group
#define NT 64
#define NH 512
#define NM 128
#define NR 4
#define NW 64
#define NI 768          // controller input size (H + R*W)
#define NXI 471         // interface vector size
#define NG 2048         // gate rows
#define EPSF 1e-6f
#define MS 65           // mem row stride (+1 pad)

// per-group roles (local = bid&63): [0,8) state | [8,40) gates | [40,48) xi | [48,64) out

// ws layout (float offsets). pub* parity double-buffered, indexed by global batch.
#define WS_LINK  0                                 // [32][128*128]
#define WS_PUBH  (WS_LINK + NBATCH*NM*NM)          // [2][32][512]
#define WS_PUBRV (WS_PUBH + 2*NBATCH*NH)           // [2][32][256]
#define WS_PUBG  (WS_PUBRV + 2*NBATCH*NR*NW)       // [2][32][2048]
#define WS_PUBXI (WS_PUBG + 2*NBATCH*NG)           // [2][32][480]
#define WS_CNT   (WS_PUBXI + 2*NBATCH*480)         // 4 groups x 5 counters x 16 uints
// per-group counter offsets (uints; one 64B line each)
#define C_SH  0     // h published:  8 init + 8/step -> 8(t+2)
#define C_SR  16    // rv published: 8 init + 8/step -> 8(t+2)
#define C_G   32    // gates done: 32/step -> 32(t+1)
#define C_X   48    // xi done: 8/step -> 8(t+1)
#define C_O   64    // out done: 16/step -> 16(t+1)
#define C_STRIDE 80
#define C_TOT (NGRP*C_STRIDE)

__device__ __forceinline__ float sigm(float x){ return 1.0f/(1.0f+expf(-x)); }
__device__ __forceinline__ float sftp(float x){ return fmaxf(x,0.0f)+log1pf(expf(-fabsf(x))); }
__device__ __forceinline__ float dot4(float4 a, float4 b){
    return a.x*b.x + a.y*b.y + a.z*b.z + a.w*b.w;
}
__device__ __forceinline__ float wave_red(float v){
    #pragma unroll
    for (int o = 32; o > 0; o >>= 1) v += __shfl_down(v, o);
    return v;
}
// LLC-coherent accessors (bypass L2, no invalidates) — proven r7-r14
__device__ __forceinline__ void cstore(float* p, float v){
    __hip_atomic_store(p, v, __ATOMIC_RELAXED, __HIP_MEMORY_SCOPE_AGENT);
}
__device__ __forceinline__ float cload(const float* p){
    return __hip_atomic_load(p, __ATOMIC_RELAXED, __HIP_MEMORY_SCOPE_AGENT);
}
// ONE thread polls ONE line (r11/r14-proven)
__device__ __forceinline__ void fwaitf(unsigned int* c, unsigned int target,
                                       int tid){
    if (tid == 0) {
        while (__hip_atomic_load(c, __ATOMIC_RELAXED,
                                 __HIP_MEMORY_SCOPE_AGENT) < target)
            __builtin_amdgcn_s_sleep(2);
    }
    __syncthreads();
}
__device__ __forceinline__ void fbump(unsigned int* c, int tid){
    __syncthreads();   // drain all waves' stores first
    if (tid == 0)
        __hip_atomic_fetch_add(c, 1u, __ATOMIC_RELEASE,
                               __HIP_MEMORY_SCOPE_AGENT);
}

__global__ void dnc_zero(float* ws){
    unsigned int* z = (unsigned int*)(ws + WS_CNT);
    if (threadIdx.x < C_TOT) z[threadIdx.x] = 0u;
}

// ---- pooled LDS (floats) ----
#define O_MEM 0
#define O_H   8320
#define O_C   8832
#define O_RW  9344
#define O_WWO 9856
#define O_WWN 9984
#define O_USG 10112
#define O_PRC 10240
#define O_XI  10368
#define O_KEY 10840
#define O_WK  11096
#define O_ER  11160
#define O_WV  11224
#define O_RS  11288
#define O_FG  11292
#define O_MD  11296
#define O_NK  11308
#define O_SC  11312
#define O_NMO 11320
#define O_NMN 11448
#define O_WCW 11576
#define O_UU  11704
#define O_SU  11832
#define O_CUM 11960
#define O_RNK 12088
#define O_CCW 12216
#define O_FWD 12728
#define O_RV  13240
#define O_RED 13496
#define S_SZ  13504
#define O_ACC 8192      // gates role: early partials [16 waves][32 slots]

__global__ __launch_bounds__(TPB) void dnc_grp(
    const float* __restrict__ x, const float* __restrict__ W_ih,
    const float* __restrict__ W_hh, const float* __restrict__ b_ih,
    const float* __restrict__ b_hh, const float* __restrict__ W_xi,
    const float* __restrict__ b_xi, const float* __restrict__ W_o,
    const float* __restrict__ b_o, float* __restrict__ out,
    float* __restrict__ ws)
{
    __shared__ __align__(16) float S[S_SZ];

    const int tid   = threadIdx.x;
    const int wv    = tid >> 6;
    const int l     = tid & 63;
    const int g     = blockIdx.x >> 6;      // group 0..3
    const int local = blockIdx.x & 63;
    const int gb0   = g * GBAT;             // first global batch of group

    float* __restrict__ pubH  = ws + WS_PUBH;
    float* __restrict__ pubRV = ws + WS_PUBRV;
    float* __restrict__ pubG  = ws + WS_PUBG;
    float* __restrict__ pubXI = ws + WS_PUBXI;
    unsigned int* __restrict__ CNT = (unsigned int*)(ws + WS_CNT) + g*C_STRIDE;

    if (local < GBAT) {
        // ========================= STATE block =========================
        const int b = gb0 + local;
        float* __restrict__ lk = ws + WS_LINK + (size_t)b*NM*NM;
        float* mem = S+O_MEM;  float* hS = S+O_H;   float* cS = S+O_C;
        float* rwS = S+O_RW;   float* wwO = S+O_WWO; float* wwN = S+O_WWN;
        float* usg = S+O_USG;  float* prc = S+O_PRC; float* xiS = S+O_XI;
        float* keys = S+O_KEY; float* wkey = S+O_WK; float* ers = S+O_ER;
        float* wvec = S+O_WV;  float* rstr = S+O_RS; float* fgte = S+O_FG;
        float* modes = S+O_MD; float* nkey = S+O_NK; float* sc = S+O_SC;
        float* nmo = S+O_NMO;  float* nmn = S+O_NMN; float* wcw = S+O_WCW;
        float* uu = S+O_UU;    float* su = S+O_SU;   float* cum = S+O_CUM;
        int*   rnk = (int*)(S+O_RNK);
        float* ccw = S+O_CCW;  float* fwdT = S+O_FWD; float* rv = S+O_RV;
        float* red = S+O_RED;

        for (int e = tid; e < NM*NM; e += TPB) lk[e] = 0.0f;
        for (int e = tid; e < NM*NW; e += TPB) mem[(e>>6)*MS + (e&63)] = EPSF;
        for (int e = tid; e < NH; e += TPB){ hS[e]=0.0f; cS[e]=0.0f; }
        for (int e = tid; e < NR*NM; e += TPB) rwS[e]=0.0f;
        for (int e = tid; e < NM; e += TPB){ wwO[e]=0.0f; usg[e]=0.0f; prc[e]=0.0f; }
        // publish h_{-1}=0, rv_{-1}=0 into parity 1
        if (tid < NH)    cstore(&pubH[(size_t)1*NBATCH*NH + b*NH + tid], 0.0f);
        if (tid < NR*NW) cstore(&pubRV[(size_t)1*NBATCH*NR*NW + b*NR*NW + tid], 0.0f);
        fbump(&CNT[C_SH], tid);
        fbump(&CNT[C_SR], tid);

        for (int t = 0; t < NT; ++t) {
            const int par = t & 1;
            // gates(t) ready
            fwaitf(&CNT[C_G], 32u*(unsigned)(t+1), tid);
            {
                const float* gb = pubG + ((size_t)par*NBATCH + b)*NG;
                if (tid < NH) {
                    float ig = sigm(cload(&gb[tid]));
                    float fg = sigm(cload(&gb[NH + tid]));
                    float gg = tanhf(cload(&gb[2*NH + tid]));
                    float og = sigm(cload(&gb[3*NH + tid]));
                    float c = fg*cS[tid] + ig*gg;
                    cS[tid] = c;
                    hS[tid] = og*tanhf(c);
                }
            }
            __syncthreads();
            // out(t-2) done before overwriting its h/rv parity
            if (t >= 2) fwaitf(&CNT[C_O], 16u*(unsigned)(t-1), tid);
            if (tid < NH) cstore(&pubH[(size_t)par*NBATCH*NH + b*NH + tid], hS[tid]);
            fbump(&CNT[C_SH], tid);

            // nmo — overlaps xi compute
            #pragma unroll
            for (int ri = 0; ri < 8; ++ri) {
                int row = wv*8 + ri;
                float v = mem[row*MS + l];
                float s2 = wave_red(v*v);
                if (l == 0) nmo[row] = sqrtf(s2);
            }
            __syncthreads();

            // xi(t) ready
            fwaitf(&CNT[C_X], 8u*(unsigned)(t+1), tid);
            if (tid < NXI) xiS[tid] = cload(&pubXI[(size_t)par*NBATCH*480 + b*480 + tid]);
            __syncthreads();

            // E1: unpack interface
            if (tid < 256)       keys[tid] = tanhf(xiS[tid]);
            else if (tid < 260)  rstr[tid-256] = sftp(xiS[tid]);
            else if (tid < 324)  wkey[tid-260] = tanhf(xiS[tid]);
            else if (tid == 324) sc[0] = sftp(xiS[324]);
            else if (tid < 389)  ers[tid-325] = sigm(xiS[tid]);
            else if (tid < 453)  wvec[tid-389] = tanhf(xiS[tid]);
            else if (tid < 457)  fgte[tid-453] = sigm(xiS[tid]);
            else if (tid == 457) sc[1] = sigm(xiS[457]);
            else if (tid == 458) sc[2] = sigm(xiS[458]);
            else if (tid < 463) {
                int r = tid - 459;
                float a0=xiS[459+3*r], a1=xiS[460+3*r], a2=xiS[461+3*r];
                float mx = fmaxf(a0, fmaxf(a1, a2));
                float e0=expf(a0-mx), e1=expf(a1-mx), e2=expf(a2-mx);
                float si = 1.0f/(e0+e1+e2);
                modes[3*r]=e0*si; modes[3*r+1]=e1*si; modes[3*r+2]=e2*si;
            }
            __syncthreads();

            // E2a: key norms
            if (tid < NR) {
                float ssum = 0.0f;
                for (int w = 0; w < NW; ++w) { float v = keys[tid*NW+w]; ssum += v*v; }
                nkey[tid] = sqrtf(ssum);
            } else if (tid == NR) {
                float ssum = 0.0f;
                for (int w = 0; w < NW; ++w) { float v = wkey[w]; ssum += v*v; }
                sc[3] = sqrtf(ssum);
            }
            // E2b: usage + uu (fused)
            if (tid >= 64 && tid < 64+NM) {
                int m = tid - 64;
                float u = usg[m];
                u = u + (1.0f - u)*wwO[m];
                float psi = 1.0f;
                #pragma unroll
                for (int r = 0; r < NR; ++r) psi *= (1.0f - fgte[r]*rwS[r*NM+m]);
                u *= psi;
                usg[m] = u;
                uu[m] = 5e-6f + (1.0f - 5e-6f)*u;
            }
            __syncthreads();

            // F1: write-content logits
            if (tid < NM) {
                float d = 0.0f;
                for (int w = 0; w < NW; ++w) d += wkey[w]*mem[tid*MS+w];
                wcw[tid] = d/(sc[3]*nmo[tid] + EPSF) * sc[0];
            }
            __syncthreads();
            // F2: softmax over 128
            if (tid < 64) {
                float v = fmaxf(wcw[tid], wcw[tid+64]);
                #pragma unroll
                for (int o = 32; o > 0; o >>= 1) v = fmaxf(v, __shfl_down(v, o));
                if (tid == 0) red[0] = v;
            }
            __syncthreads();
            if (tid < NM) wcw[tid] = expf(wcw[tid] - red[0]);
            __syncthreads();
            if (tid < 64) {
                float v = wave_red(wcw[tid] + wcw[tid+64]);
                if (tid == 0) red[0] = 1.0f/v;
            }
            __syncthreads();
            if (tid < NM) wcw[tid] *= red[0];
            __syncthreads();

            // G2: stable rank
            if (tid < NM) {
                float um = uu[tid]; int rk = 0;
                for (int j = 0; j < NM; ++j) {
                    float uj = uu[j];
                    rk += (uj < um) || (uj == um && j < tid);
                }
                rnk[tid] = rk;
                su[rk] = um;
            }
            __syncthreads();
            // G3: product scan (wave 0)
            if (tid < 64) {
                float a = su[tid], bb = su[64+tid];
                #pragma unroll
                for (int o = 1; o < 64; o <<= 1) {
                    float ta = __shfl_up(a, o);
                    float tb = __shfl_up(bb, o);
                    if (tid >= o) { a *= ta; bb *= tb; }
                }
                float P0 = __shfl(a, 63);
                cum[tid] = a;
                cum[64+tid] = P0*bb;
            }
            __syncthreads();
            // G4: alloc + write weighting
            if (tid < NM) {
                int rk = rnk[tid];
                float excl = (rk == 0) ? 1.0f : cum[rk-1];
                float al = (1.0f - uu[tid])*excl;
                wwN[tid] = sc[2]*(sc[1]*al + (1.0f - sc[1])*wcw[tid]);
            }
            __syncthreads();
            // G5: sum(wwN)
            if (tid < 64) {
                float v = wave_red(wwN[tid] + wwN[tid+64]);
                if (tid == 0) sc[4] = v;
            }
            __syncthreads();

            // H (fused): mem erase/write + new norms + link
            #pragma unroll
            for (int ri = 0; ri < 8; ++ri) {
                int row = wv*8 + ri;
                float wm = wwN[row];
                float v = mem[row*MS + l];
                float nv = v*(1.0f - wm*ers[l]) + wm*wvec[l];
                mem[row*MS + l] = nv;
                float s2 = wave_red(nv*nv);
                if (l == 0) nmn[row] = sqrtf(s2);
            }
            for (int e = tid; e < NM*NM; e += TPB) {
                int i = e >> 7, j = e & 127;
                float nl = (i == j) ? 0.0f
                         : (1.0f - wwN[i] - wwN[j])*lk[e] + wwN[i]*prc[j];
                lk[e] = nl;
            }
            __syncthreads();
            // H3: precedence
            if (tid < NM) prc[tid] = (1.0f - sc[4])*prc[tid] + wwN[tid];
            __syncthreads();

            // I: read-content logits + per-r softmax
            if (tid < NR*NM) {
                int r = tid >> 7, m = tid & 127;
                float d = 0.0f;
                for (int w = 0; w < NW; ++w) d += keys[r*NW+w]*mem[m*MS+w];
                ccw[tid] = d/(nkey[r]*nmn[m] + EPSF) * rstr[r];
            }
            __syncthreads();
            if (tid < 256) {
                int r = tid >> 6, ll = tid & 63;
                float v = fmaxf(ccw[r*NM+ll], ccw[r*NM+ll+64]);
                #pragma unroll
                for (int o = 32; o > 0; o >>= 1) v = fmaxf(v, __shfl_down(v, o));
                if (ll == 0) red[r] = v;
            }
            __syncthreads();
            if (tid < NR*NM) ccw[tid] = expf(ccw[tid] - red[tid>>7]);
            __syncthreads();
            if (tid < 256) {
                int r = tid >> 6, ll = tid & 63;
                float v = wave_red(ccw[r*NM+ll] + ccw[r*NM+ll+64]);
                if (ll == 0) red[4+r] = 1.0f/v;
            }
            __syncthreads();
            if (tid < NR*NM) ccw[tid] *= red[4+(tid>>7)];
            __syncthreads();

            // J1: fwd[r][m]
            {
                const int p0 = wv*32;
                for (int i = 0; i < 32; ++i) {
                    const int p = p0 + i, r = p >> 7, m = p & 127;
                    float partial = lk[m*NM + l]*rwS[r*NM + l]
                                  + lk[m*NM + 64 + l]*rwS[r*NM + 64 + l];
                    partial = wave_red(partial);
                    if (l == 0) fwdT[p] = partial;
                }
            }
            __syncthreads();
            // J2: bwd + mode mix
            float rwnew = 0.0f;
            if (tid < NR*NM) {
                int r = tid >> 7, m = tid & 127;
                float bw = 0.0f;
                for (int i = 0; i < NM; ++i) bw += lk[i*NM+m]*rwS[r*NM+i];
                rwnew = modes[3*r]*bw + modes[3*r+1]*fwdT[tid] + modes[3*r+2]*ccw[tid];
            }
            __syncthreads();
            if (tid < NR*NM) rwS[tid] = rwnew;
            __syncthreads();

            // K: read vectors + publish rv
            if (tid < NR*NW) {
                int r = tid >> 6, w = tid & 63;
                float ssum = 0.0f;
                for (int m = 0; m < NM; ++m) ssum += rwS[r*NM+m]*mem[m*MS+w];
                rv[tid] = ssum;
                cstore(&pubRV[(size_t)par*NBATCH*NR*NW + b*NR*NW + tid], ssum);
            }
            fbump(&CNT[C_SR], tid);

            if (tid < NM) wwO[tid] = wwN[tid];
            __syncthreads();
        }
    } else if (local < 8 + 32) {
        // ================= GATES block (64 rows; wrv pinned, wx/wh streamed) ===
        const int gl = local - 8;
        float4 wrv[4]; float bias[4];
        #pragma unroll
        for (int k = 0; k < 4; ++k) {
            const int r = gl*64 + wv + 16*k;
            wrv[k] = ((const float4*)(W_ih + (size_t)r*NI))[128 + l];
            bias[k] = b_ih[r] + b_hh[r];
        }
        float* accS = S + O_ACC;   // [16 waves][32 slots = 4k x 8bi]

        for (int t = 0; t < NT; ++t) {
            const int par = t & 1, parp = (t+1) & 1;
            // EARLY: x(t) + h(t-1); weights streamed from L2 (off critical path)
            fwaitf(&CNT[C_SH], 8u*(unsigned)(t+1), tid);
            const float* hIn = pubH + (size_t)parp*NBATCH*NH;
            #pragma unroll
            for (int it = 0; it < 4; ++it) { int idx = tid + it*1024;
                int bi = idx >> 9, k = idx & 511;
                S[bi*512 + k] = x[((size_t)(gb0+bi)*NT + t)*NH + k]; }
            #pragma unroll
            for (int it = 0; it < 4; ++it) { int idx = tid + it*1024;
                int bi = idx >> 9, k = idx & 511;
                S[4096 + bi*512 + k] = cload(&hIn[(gb0+bi)*NH + k]); }
            __syncthreads();
            #pragma unroll
            for (int k = 0; k < 4; ++k) {
                const int r = gl*64 + wv + 16*k;
                const float4* WA = (const float4*)(W_ih + (size_t)r*NI);
                const float4* WB = (const float4*)(W_hh + (size_t)r*NH);
                float4 wx0 = WA[l], wx1 = WA[l+64];
                float4 wh0 = WB[l], wh1 = WB[l+64];
                #pragma unroll
                for (int bi = 0; bi < GBAT; ++bi) {
                    const float4* X4 = (const float4*)(S + bi*512);
                    const float4* H4 = (const float4*)(S + 4096 + bi*512);
                    float a = dot4(wx0, X4[l]) + dot4(wx1, X4[l+64])
                            + dot4(wh0, H4[l]) + dot4(wh1, H4[l+64]);
                    a = wave_red(a);
                    if (l == 0) accS[wv*32 + k*8 + bi] = a;
                }
            }
            __syncthreads();
            // LATE: rv(t-1) — critical path
            fwaitf(&CNT[C_SR], 8u*(unsigned)(t+1), tid);
            const float* rIn = pubRV + (size_t)parp*NBATCH*NR*NW;
            #pragma unroll
            for (int it = 0; it < 2; ++it) { int idx = tid + it*1024;
                int bi = idx >> 8, k = idx & 255;
                S[bi*256 + k] = cload(&rIn[(gb0+bi)*NR*NW + k]); }
            __syncthreads();
            float* gOut = pubG + (size_t)par*NBATCH*NG;
            #pragma unroll
            for (int k = 0; k < 4; ++k) {
                const int r = gl*64 + wv + 16*k;
                #pragma unroll
                for (int bi = 0; bi < GBAT; ++bi) {
                    const float4* RV4 = (const float4*)(S + bi*256);
                    float d = dot4(wrv[k], RV4[l]);
                    d = wave_red(d);
                    if (l == 0) cstore(&gOut[(size_t)(gb0+bi)*NG + r],
                                       d + accS[wv*32 + k*8 + bi] + bias[k]);
                }
            }
            fbump(&CNT[C_G], tid);
        }
    } else if (local < 8 + 32 + 8) {
        // ================= XI block (59 rows, pinned) ==================
        const int xg = local - 40;
        float4 xa0[4], xa1[4]; float xb[4]; bool av[4]; int xrow[4];
        #pragma unroll
        for (int k = 0; k < 4; ++k) {
            const int rr = 16*k + wv;
            const int r = xg*59 + rr;
            av[k] = (rr < 59) && (r < NXI);
            xrow[k] = r;
            if (av[k]) {
                const float4* WX = (const float4*)(W_xi + (size_t)r*NH);
                xa0[k] = WX[l]; xa1[k] = WX[l+64]; xb[k] = b_xi[r];
            }
        }
        for (int t = 0; t < NT; ++t) {
            const int par = t & 1;
            fwaitf(&CNT[C_SH], 8u*(unsigned)(t+2), tid);    // h(t)
            const float* hIn = pubH + (size_t)par*NBATCH*NH;
            float* xOut = pubXI + (size_t)par*NBATCH*480;
            #pragma unroll
            for (int it = 0; it < 4; ++it) { int idx = tid + it*1024;
                int bi = idx >> 9, k = idx & 511;
                S[bi*512 + k] = cload(&hIn[(gb0+bi)*NH + k]); }
            __syncthreads();
            #pragma unroll
            for (int k = 0; k < 4; ++k) {
                if (av[k]) {
                    #pragma unroll
                    for (int bi = 0; bi < GBAT; ++bi) {
                        const float4* H4 = (const float4*)(S + bi*512);
                        float a = dot4(xa0[k], H4[l]) + dot4(xa1[k], H4[l+64]);
                        a = wave_red(a);
                        if (l == 0) cstore(&xOut[(size_t)(gb0+bi)*480 + xrow[k]],
                                           a + xb[k]);
                    }
                }
            }
            fbump(&CNT[C_X], tid);
        }
    } else {
        // ================= OUT block (32 rows, pinned) =================
        const int og = local - 48;
        float4 o0[2], o1[2], o2[2]; float ob[2];
        #pragma unroll
        for (int k = 0; k < 2; ++k) {
            const int r = og*32 + wv + 16*k;
            const float4* WO = (const float4*)(W_o + (size_t)r*NI);
            o0[k] = WO[l]; o1[k] = WO[l+64]; o2[k] = WO[128+l]; ob[k] = b_o[r];
        }
        for (int t = 0; t < NT; ++t) {
            const int par = t & 1;
            fwaitf(&CNT[C_SH], 8u*(unsigned)(t+2), tid);    // h(t)
            fwaitf(&CNT[C_SR], 8u*(unsigned)(t+2), tid);    // rv(t)
            const float* hIn = pubH + (size_t)par*NBATCH*NH;
            const float* rIn = pubRV + (size_t)par*NBATCH*NR*NW;
            #pragma unroll
            for (int it = 0; it < 4; ++it) { int idx = tid + it*1024;
                int bi = idx >> 9, k = idx & 511;
                S[bi*768 + k] = cload(&hIn[(gb0+bi)*NH + k]); }
            #pragma unroll
            for (int it = 0; it < 2; ++it) { int idx = tid + it*1024;
                int bi = idx >> 8, k = idx & 255;
                S[bi*768 + 512 + k] = cload(&rIn[(gb0+bi)*NR*NW + k]); }
            __syncthreads();
            #pragma unroll
            for (int k = 0; k < 2; ++k) {
                const int r = og*32 + wv + 16*k;
                #pragma unroll
                for (int bi = 0; bi < GBAT; ++bi) {
                    const float4* B4 = (const float4*)(S + bi*768);
                    float a = dot4(o0[k],B4[l]) + dot4(o1[k],B4[l+64])
                            + dot4(o2[k],B4[128+l]);
                    a = wave_red(a);
                    if (l == 0) out[((size_t)(gb0+bi)*NT + t)*NH + r] = a + ob[k];
                }
            }
            fbump(&CNT[C_O], tid);
        }
    }
}

extern "C" void kernel_launch(void* const* d_in, const int* in_sizes, int n_in,
                              void* d_out, int out_size, void* d_ws, size_t ws_size,
                              hipStream_t stream) {
    (void)in_sizes; (void)n_in; (void)out_size; (void)ws_size;
    const float* x    = (const float*)d_in[0];
    const float* W_ih = (const float*)d_in[1];
    const float* W_hh = (const float*)d_in[2];
    const float* b_ih = (const float*)d_in[3];
    const float* b_hh = (const float*)d_in[4];
    const float* W_xi = (const float*)d_in[5];
    const float* b_xi = (const float*)d_in[6];
    const float* W_o  = (const float*)d_in[7];
    const float* b_o  = (const float*)d_in[8];
    float* out = (float*)d_out;
    float* ws  = (float*)d_ws;

    dnc_zero<<<1, 1024, 0, stream>>>(ws);

    void* args[] = { (void*)&x, (void*)&W_ih, (void*)&W_hh, (void*)&b_ih,
                     (void*)&b_hh, (void*)&W_xi, (void*)&b_xi, (void*)&W_o,
                     (void*)&b_o, (void*)&out, (void*)&ws };
    hipLaunchCooperativeKernel((void*)dnc_grp, dim3(NBLK), dim3(TPB),
                               args, 0, stream);
}